// Round 2
// baseline (2236.810 us; speedup 1.0000x reference)
//
#include <hip/hip_runtime.h>
#include <stdint.h>
#include <stddef.h>

// ---------------------------------------------------------------------------
// AddInterpolant: xt/dt_xt of a 4-layer MLP flow interpolant, B=65536.
//   z=[x0|x1|t] (513)->1024->1024->1024->256, relu between; JVP wrt t-slot.
//   Tangent into layer1 is r1 = W1[512,:] (sample-independent) -> epilogue.
//   Fused per-layer kernel: H-GEMM and U-GEMM share the W tile; two
//   accumulator sets; relu mask applied in-register.
//
// R1 post-mortem: contiguous-chunk XCD swizzle spread the 8 XCDs across the
//   whole M range -> L3 thrash -> partial-line writebacks (WRITE 133->706MB)
//   -> 2x regression. Lesson: default dispatch order's marching-band L3
//   locality must be preserved.
// R2: band-preserving XCD swizzle. XCD g (= id&7) takes panels by=8j+g with
//   all bx consecutive: per-panel A reuse lands in ONE L2 (kills the 4x
//   over-fetch) while the global by band marches exactly like the default
//   order (keeps R0's perfect write behavior). Keep __launch_bounds__(256,3)
//   (R1 showed 3 blocks/CU achieved, no spill signature).
// ---------------------------------------------------------------------------

typedef unsigned short u16;
typedef __attribute__((ext_vector_type(8))) short short8;
typedef __attribute__((ext_vector_type(4))) float f32x4;

#define BM 128
#define BN 128
#define BK 64
#define BATCH 65536
#define SDIM 256
#define HDIM 1024

__device__ __forceinline__ u16 f2bf(float f) {
  unsigned int u = __float_as_uint(f);
  u += 0x7FFFu + ((u >> 16) & 1u);   // round-to-nearest-even
  return (u16)(u >> 16);
}

__device__ __forceinline__ void gload_lds16(const void* g, void* l) {
  // 16B/lane; LDS dest = wave-uniform base + lane*16 (hardware rule).
  __builtin_amdgcn_global_load_lds(
      (const __attribute__((address_space(1))) unsigned int*)g,
      (__attribute__((address_space(3))) unsigned int*)l, 16, 0, 0);
}

struct EpiArgs {
  const float* bias;
  const float* r1;    // W1 row 512 (f32)
  const float* t;     // chunk-local base
  const float* x0;
  const float* x1;
  u16*   out_h;
  u16*   out_u;
  float* out_xt;
  float* out_dt;
};

// C = A[M,K] @ Bt[N,K]^T with optional second A (tangent path), bf16 in,
// f32 accumulate. 128x128x64 tiles, global_load_lds(16B), XOR k-chunk
// swizzle applied on the GLOBAL side (LDS stays linear per the
// global_load_lds wave-uniform-base constraint).
// EPI 0 (HASU=0): layer1. pre = acc_h + b[n] + t[m]*r1[n];
//                 H=relu(pre); U=(pre>0)?r1[n]:0.
// EPI 1 (HASU=1): mid layer. pre = acc_h + b[n]; H=relu(pre);
//                 U=(pre>0)?acc_u:0.
// EPI 2 (HASU=1): layer4 + combine. fnn=acc_h+b[n]; dtfnn=acc_u;
//                 xt,dt_xt written f32.
template <int EPI, bool HASU>
__global__ __launch_bounds__(256, 3)
void fgemm(const u16* __restrict__ Ah, const u16* __restrict__ Au,
           const u16* __restrict__ Bt, int N, int K, EpiArgs e)
{
  __shared__ __align__(16) u16 Ash[BM * BK];
  __shared__ __align__(16) u16 Asu[HASU ? BM * BK : 64];
  __shared__ __align__(16) u16 Bs[BN * BK];

  const int tid  = threadIdx.x;
  const int wave = tid >> 6;
  const int lane = tid & 63;
  const int hi   = lane >> 4;   // 0..3
  const int ln   = lane & 15;

  // --- R2 band-preserving XCD swizzle. Hardware dispatch round-robins
  // linear id over the 8 XCDs (XCD ~ id&7, per-XCD step s = id>>3).
  // Assign: bx = s % nbx, by = (s/nbx)*8 + (id&7).
  //   * the 8 bx-siblings of a by panel are consecutive s on ONE XCD
  //     -> A panel fetched into one L2, once (was: 8 different L2s).
  //   * at any instant the XCDs cover a contiguous 8-wide by band ->
  //     identical L3 marching-band behavior to the default order
  //     (R1's chunked variant broke this and 5x'd WRITE_SIZE).
  const int nbx = gridDim.x;
  int bx = blockIdx.x, by = blockIdx.y;
  if ((gridDim.y & 7) == 0) {                  // bijective iff 8 | gy
    const int id = by * nbx + bx;
    const int g  = id & 7;
    const int s  = id >> 3;
    bx = s % nbx;
    by = (s / nbx) * 8 + g;
  }
  const int bn = bx * BN;
  const int bm = by * BM;

  const int wm = (wave >> 1) * 64;
  const int wn = (wave & 1) * 64;

  f32x4 acch[4][4] = {};
  f32x4 accu[4][4] = {};

  const int srow = lane >> 3;  // row within 8-row chunk
  const int ssc  = lane & 7;   // storage 16B-chunk slot within row

  for (int k0 = 0; k0 < K; k0 += BK) {
#pragma unroll
    for (int c = 0; c < 4; ++c) {
      const int ch  = wave * 4 + c;          // 0..15 -> 8 rows each
      const int row = ch * 8 + srow;
      const int lc  = ssc ^ (row & 7);       // logical k-chunk for this slot
      gload_lds16(Ah + (size_t)(bm + row) * K + k0 + lc * 8, &Ash[ch * 512]);
      gload_lds16(Bt + (size_t)(bn + row) * K + k0 + lc * 8, &Bs[ch * 512]);
      if constexpr (HASU)
        gload_lds16(Au + (size_t)(bm + row) * K + k0 + lc * 8, &Asu[ch * 512]);
    }
    asm volatile("s_waitcnt vmcnt(0)" ::: "memory");
    __syncthreads();

#pragma unroll
    for (int kk = 0; kk < BK; kk += 32) {
      const int sc = ((kk >> 3) + hi) ^ (ln & 7);  // un-swizzle on read
      short8 ah[4], au[4], bb[4];
#pragma unroll
      for (int i = 0; i < 4; ++i) {
        const int ro = (wm + i * 16 + ln) * BK + sc * 8;  // row&7 == ln&7
        ah[i] = *(const short8*)&Ash[ro];
        if constexpr (HASU) au[i] = *(const short8*)&Asu[ro];
      }
#pragma unroll
      for (int i = 0; i < 4; ++i)
        bb[i] = *(const short8*)&Bs[(wn + i * 16 + ln) * BK + sc * 8];
#pragma unroll
      for (int mi = 0; mi < 4; ++mi)
#pragma unroll
        for (int ni = 0; ni < 4; ++ni) {
          acch[mi][ni] = __builtin_amdgcn_mfma_f32_16x16x32_bf16(
              ah[mi], bb[ni], acch[mi][ni], 0, 0, 0);
          if constexpr (HASU)
            accu[mi][ni] = __builtin_amdgcn_mfma_f32_16x16x32_bf16(
                au[mi], bb[ni], accu[mi][ni], 0, 0, 0);
        }
    }
    __syncthreads();
  }

  // C/D layout: col = lane&15, row = (lane>>4)*4 + reg  [m89].
#pragma unroll
  for (int mi = 0; mi < 4; ++mi) {
#pragma unroll
    for (int ni = 0; ni < 4; ++ni) {
      const int n = bn + wn + ni * 16 + ln;
#pragma unroll
      for (int r = 0; r < 4; ++r) {
        const size_t m  = (size_t)(bm + wm + mi * 16 + hi * 4 + r);
        const size_t ix = m * (size_t)N + n;
        const float vh = acch[mi][ni][r];
        if constexpr (EPI == 0) {
          const float r1n = e.r1[n];
          const float pre = vh + e.bias[n] + e.t[m] * r1n;
          e.out_h[ix] = f2bf(fmaxf(pre, 0.f));
          e.out_u[ix] = (pre > 0.f) ? f2bf(r1n) : (u16)0;
        } else if constexpr (EPI == 1) {
          const float vu  = accu[mi][ni][r];
          const float pre = vh + e.bias[n];
          e.out_h[ix] = f2bf(fmaxf(pre, 0.f));
          e.out_u[ix] = (pre > 0.f) ? f2bf(vu) : (u16)0;
        } else {
          const float vu  = accu[mi][ni][r];
          const float fnn = vh + e.bias[n];
          const float tt  = e.t[m];
          const float a   = e.x0[ix];
          const float b   = e.x1[ix];
          const float w   = tt * (1.f - tt);
          e.out_xt[ix] = (1.f - tt) * a + tt * b + w * fnn;
          e.out_dt[ix] = b - a + (1.f - 2.f * tt) * fnn + w * vu;
        }
      }
    }
  }
}

// A0 = bf16([x0 | x1]) chunk, [CB, 512]; one thread per 4 elements.
__global__ void prep_z(const float* __restrict__ x0, const float* __restrict__ x1,
                       u16* __restrict__ A0)
{
  const int idx = blockIdx.x * blockDim.x + threadIdx.x;
  const int m = idx >> 7;        // 128 4-elem chunks per row
  const int c = idx & 127;
  const float* src = (c < 64) ? (x0 + (size_t)m * 256 + c * 4)
                              : (x1 + (size_t)m * 256 + (c - 64) * 4);
  const float4 v = *(const float4*)src;
  uint2 pk;
  pk.x = (unsigned)f2bf(v.x) | ((unsigned)f2bf(v.y) << 16);
  pk.y = (unsigned)f2bf(v.z) | ((unsigned)f2bf(v.w) << 16);
  *(uint2*)&A0[(size_t)m * 512 + c * 4] = pk;
}

// Wt[N,K] bf16 <- W[K,N] f32, 32x32 LDS tile transpose.
__global__ void transpose_cast(const float* __restrict__ W, u16* __restrict__ Wt,
                               int K, int N)
{
  __shared__ float tile[32][33];
  const int tx = threadIdx.x & 31;
  const int ty = threadIdx.x >> 5;  // 0..7
  const int k0 = blockIdx.x * 32;
  const int n0 = blockIdx.y * 32;
#pragma unroll
  for (int i = 0; i < 32; i += 8)
    tile[ty + i][tx] = W[(size_t)(k0 + ty + i) * N + n0 + tx];
  __syncthreads();
#pragma unroll
  for (int i = 0; i < 32; i += 8)
    Wt[(size_t)(n0 + ty + i) * K + k0 + tx] = f2bf(tile[tx][ty + i]);
}

extern "C" void kernel_launch(void* const* d_in, const int* in_sizes, int n_in,
                              void* d_out, int out_size, void* d_ws, size_t ws_size,
                              hipStream_t stream)
{
  const float* x0 = (const float*)d_in[0];
  const float* x1 = (const float*)d_in[1];
  const float* t  = (const float*)d_in[2];
  const float* W1 = (const float*)d_in[3];
  const float* b1 = (const float*)d_in[4];
  const float* W2 = (const float*)d_in[5];
  const float* b2 = (const float*)d_in[6];
  const float* W3 = (const float*)d_in[7];
  const float* b3 = (const float*)d_in[8];
  const float* W4 = (const float*)d_in[9];
  const float* b4 = (const float*)d_in[10];

  char* ws = (char*)d_ws;
  const size_t WB1 = (size_t)512 * HDIM * 2;   // 1 MiB
  const size_t WB2 = (size_t)HDIM * HDIM * 2;  // 2 MiB
  const size_t WB4 = (size_t)HDIM * SDIM * 2;  // 0.5 MiB
  u16* Wt1 = (u16*)(ws);
  u16* Wt2 = (u16*)(ws + WB1);
  u16* Wt3 = (u16*)(ws + WB1 + WB2);
  u16* Wt4 = (u16*)(ws + WB1 + 2 * WB2);
  const size_t wmark = WB1 + 2 * WB2 + WB4;    // 5.5 MiB
  char* act = ws + wmark;

  // Adaptive chunking: per-chunk activations = 4 buffers of CB*2048 B
  // (A0 chunk aliases the Hb buffer). Pick nc so everything fits ws_size.
  int nc = 1;
  while (nc < 64 && wmark + (size_t)(BATCH / nc) * 8192 > ws_size) nc <<= 1;
  const int CB = BATCH / nc;

  u16* Ha = (u16*)(act);
  u16* Ua = (u16*)(act + (size_t)CB * 2048);
  u16* Hb = (u16*)(act + (size_t)CB * 4096);
  u16* Ub = (u16*)(act + (size_t)CB * 6144);
  u16* A0c = Hb;  // alias: A0 chunk (CB*1024 B) dead after layer 1

  transpose_cast<<<dim3(16, 32), 256, 0, stream>>>(W1, Wt1, 512, HDIM);
  transpose_cast<<<dim3(32, 32), 256, 0, stream>>>(W2, Wt2, HDIM, HDIM);
  transpose_cast<<<dim3(32, 32), 256, 0, stream>>>(W3, Wt3, HDIM, HDIM);
  transpose_cast<<<dim3(32, 8),  256, 0, stream>>>(W4, Wt4, HDIM, SDIM);

  const float* r1 = W1 + (size_t)512 * HDIM;   // last row of W1
  float* out_xt = (float*)d_out;
  float* out_dt = (float*)d_out + (size_t)BATCH * SDIM;

  for (int c = 0; c < nc; ++c) {
    const size_t mb = (size_t)c * CB;
    const dim3 gMid(HDIM / BN, CB / BM);
    const dim3 gOut(SDIM / BN, CB / BM);

    prep_z<<<(CB * 128) / 256, 256, 0, stream>>>(x0 + mb * SDIM, x1 + mb * SDIM, A0c);

    { EpiArgs e{}; e.bias = b1; e.r1 = r1; e.t = t + mb;
      e.out_h = Ha; e.out_u = Ua;
      fgemm<0, false><<<gMid, 256, 0, stream>>>(A0c, nullptr, Wt1, HDIM, 512, e); }

    { EpiArgs e{}; e.bias = b2; e.out_h = Hb; e.out_u = Ub;
      fgemm<1, true><<<gMid, 256, 0, stream>>>(Ha, Ua, Wt2, HDIM, HDIM, e); }

    { EpiArgs e{}; e.bias = b3; e.out_h = Ha; e.out_u = Ua;
      fgemm<1, true><<<gMid, 256, 0, stream>>>(Hb, Ub, Wt3, HDIM, HDIM, e); }

    { EpiArgs e{}; e.bias = b4; e.t = t + mb;
      e.x0 = x0 + mb * SDIM; e.x1 = x1 + mb * SDIM;
      e.out_xt = out_xt + mb * SDIM; e.out_dt = out_dt + mb * SDIM;
      fgemm<2, true><<<gOut, 256, 0, stream>>>(Ha, Ua, Wt4, SDIM, HDIM, e); }
  }
}

// Round 3
// 1107.256 us; speedup vs baseline: 2.0201x; 2.0201x over previous
//
#include <hip/hip_runtime.h>
#include <stdint.h>
#include <stddef.h>

// ---------------------------------------------------------------------------
// AddInterpolant: xt/dt_xt of a 4-layer MLP flow interpolant, B=65536.
//   z=[x0|x1|t] (513)->1024->1024->1024->256, relu between; JVP wrt t-slot.
//   Tangent into layer1 is r1 = W1[512,:] (sample-independent) -> epilogue.
//   Fused per-layer kernel: H-GEMM and U-GEMM share the W tile; two
//   accumulator sets; relu mask applied in-register.
//
// R1 post-mortem: launch_bounds(256,3) + scatter swizzle -> 2x regression.
// R2 post-mortem: WRITE_SIZE identical (706MB) across two DIFFERENT swizzles
//   -> the write explosion is NOT the swizzle; it's launch_bounds(256,3):
//   3 waves/SIMD caps the unified VGPR/AGPR budget at ~170/wave, but the two
//   f32x4[4][4] accumulator sets are 128 AGPRs alone -> hot-loop scratch
//   spills (VGPR_Count dropped 104->84, +573MB writes = ~1.1KB/thread,
//   MfmaUtil halved). The band-preserving swizzle DID halve read traffic
//   (FETCH 528->~283MB).
// R3: keep the band-preserving XCD swizzle, revert to launch_bounds(256,2)
//   (2 blocks/CU: 232 regs/wave fits the 256-reg budget, no spills).
// ---------------------------------------------------------------------------

typedef unsigned short u16;
typedef __attribute__((ext_vector_type(8))) short short8;
typedef __attribute__((ext_vector_type(4))) float f32x4;

#define BM 128
#define BN 128
#define BK 64
#define BATCH 65536
#define SDIM 256
#define HDIM 1024

__device__ __forceinline__ u16 f2bf(float f) {
  unsigned int u = __float_as_uint(f);
  u += 0x7FFFu + ((u >> 16) & 1u);   // round-to-nearest-even
  return (u16)(u >> 16);
}

__device__ __forceinline__ void gload_lds16(const void* g, void* l) {
  // 16B/lane; LDS dest = wave-uniform base + lane*16 (hardware rule).
  __builtin_amdgcn_global_load_lds(
      (const __attribute__((address_space(1))) unsigned int*)g,
      (__attribute__((address_space(3))) unsigned int*)l, 16, 0, 0);
}

struct EpiArgs {
  const float* bias;
  const float* r1;    // W1 row 512 (f32)
  const float* t;     // chunk-local base
  const float* x0;
  const float* x1;
  u16*   out_h;
  u16*   out_u;
  float* out_xt;
  float* out_dt;
};

// C = A[M,K] @ Bt[N,K]^T with optional second A (tangent path), bf16 in,
// f32 accumulate. 128x128x64 tiles, global_load_lds(16B), XOR k-chunk
// swizzle applied on the GLOBAL side (LDS stays linear per the
// global_load_lds wave-uniform-base constraint).
// EPI 0 (HASU=0): layer1. pre = acc_h + b[n] + t[m]*r1[n];
//                 H=relu(pre); U=(pre>0)?r1[n]:0.
// EPI 1 (HASU=1): mid layer. pre = acc_h + b[n]; H=relu(pre);
//                 U=(pre>0)?acc_u:0.
// EPI 2 (HASU=1): layer4 + combine. fnn=acc_h+b[n]; dtfnn=acc_u;
//                 xt,dt_xt written f32.
template <int EPI, bool HASU>
__global__ __launch_bounds__(256, 2)
void fgemm(const u16* __restrict__ Ah, const u16* __restrict__ Au,
           const u16* __restrict__ Bt, int N, int K, EpiArgs e)
{
  __shared__ __align__(16) u16 Ash[BM * BK];
  __shared__ __align__(16) u16 Asu[HASU ? BM * BK : 64];
  __shared__ __align__(16) u16 Bs[BN * BK];

  const int tid  = threadIdx.x;
  const int wave = tid >> 6;
  const int lane = tid & 63;
  const int hi   = lane >> 4;   // 0..3
  const int ln   = lane & 15;

  // --- R2 band-preserving XCD swizzle (kept in R3; verified FETCH 528->283MB).
  // Hardware round-robins linear id over the 8 XCDs (XCD ~ id&7 = orig bx,
  // per-XCD step s = id>>3 = orig by). Map (bx,by) -> (by%8, (by&~7)+bx):
  //   * output panel P is computed by 8 blocks with consecutive s on ONE XCD
  //     -> its A panel is fetched into exactly one L2, once.
  //   * at any instant the XCDs cover a contiguous 8-wide by band ->
  //     same L3 marching-band behavior as the default order.
  const int nbx = gridDim.x;
  int bx = blockIdx.x, by = blockIdx.y;
  if ((gridDim.y & 7) == 0) {                  // bijective iff 8 | gy
    const int id = by * nbx + bx;
    const int g  = id & 7;
    const int s  = id >> 3;
    bx = s % nbx;
    by = (s / nbx) * 8 + g;
  }
  const int bn = bx * BN;
  const int bm = by * BM;

  const int wm = (wave >> 1) * 64;
  const int wn = (wave & 1) * 64;

  f32x4 acch[4][4] = {};
  f32x4 accu[4][4] = {};

  const int srow = lane >> 3;  // row within 8-row chunk
  const int ssc  = lane & 7;   // storage 16B-chunk slot within row

  for (int k0 = 0; k0 < K; k0 += BK) {
#pragma unroll
    for (int c = 0; c < 4; ++c) {
      const int ch  = wave * 4 + c;          // 0..15 -> 8 rows each
      const int row = ch * 8 + srow;
      const int lc  = ssc ^ (row & 7);       // logical k-chunk for this slot
      gload_lds16(Ah + (size_t)(bm + row) * K + k0 + lc * 8, &Ash[ch * 512]);
      gload_lds16(Bt + (size_t)(bn + row) * K + k0 + lc * 8, &Bs[ch * 512]);
      if constexpr (HASU)
        gload_lds16(Au + (size_t)(bm + row) * K + k0 + lc * 8, &Asu[ch * 512]);
    }
    asm volatile("s_waitcnt vmcnt(0)" ::: "memory");
    __syncthreads();

#pragma unroll
    for (int kk = 0; kk < BK; kk += 32) {
      const int sc = ((kk >> 3) + hi) ^ (ln & 7);  // un-swizzle on read
      short8 ah[4], au[4], bb[4];
#pragma unroll
      for (int i = 0; i < 4; ++i) {
        const int ro = (wm + i * 16 + ln) * BK + sc * 8;  // row&7 == ln&7
        ah[i] = *(const short8*)&Ash[ro];
        if constexpr (HASU) au[i] = *(const short8*)&Asu[ro];
      }
#pragma unroll
      for (int i = 0; i < 4; ++i)
        bb[i] = *(const short8*)&Bs[(wn + i * 16 + ln) * BK + sc * 8];
#pragma unroll
      for (int mi = 0; mi < 4; ++mi)
#pragma unroll
        for (int ni = 0; ni < 4; ++ni) {
          acch[mi][ni] = __builtin_amdgcn_mfma_f32_16x16x32_bf16(
              ah[mi], bb[ni], acch[mi][ni], 0, 0, 0);
          if constexpr (HASU)
            accu[mi][ni] = __builtin_amdgcn_mfma_f32_16x16x32_bf16(
                au[mi], bb[ni], accu[mi][ni], 0, 0, 0);
        }
    }
    __syncthreads();
  }

  // C/D layout: col = lane&15, row = (lane>>4)*4 + reg  [m89].
#pragma unroll
  for (int mi = 0; mi < 4; ++mi) {
#pragma unroll
    for (int ni = 0; ni < 4; ++ni) {
      const int n = bn + wn + ni * 16 + ln;
#pragma unroll
      for (int r = 0; r < 4; ++r) {
        const size_t m  = (size_t)(bm + wm + mi * 16 + hi * 4 + r);
        const size_t ix = m * (size_t)N + n;
        const float vh = acch[mi][ni][r];
        if constexpr (EPI == 0) {
          const float r1n = e.r1[n];
          const float pre = vh + e.bias[n] + e.t[m] * r1n;
          e.out_h[ix] = f2bf(fmaxf(pre, 0.f));
          e.out_u[ix] = (pre > 0.f) ? f2bf(r1n) : (u16)0;
        } else if constexpr (EPI == 1) {
          const float vu  = accu[mi][ni][r];
          const float pre = vh + e.bias[n];
          e.out_h[ix] = f2bf(fmaxf(pre, 0.f));
          e.out_u[ix] = (pre > 0.f) ? f2bf(vu) : (u16)0;
        } else {
          const float vu  = accu[mi][ni][r];
          const float fnn = vh + e.bias[n];
          const float tt  = e.t[m];
          const float a   = e.x0[ix];
          const float b   = e.x1[ix];
          const float w   = tt * (1.f - tt);
          e.out_xt[ix] = (1.f - tt) * a + tt * b + w * fnn;
          e.out_dt[ix] = b - a + (1.f - 2.f * tt) * fnn + w * vu;
        }
      }
    }
  }
}

// A0 = bf16([x0 | x1]) chunk, [CB, 512]; one thread per 4 elements.
__global__ void prep_z(const float* __restrict__ x0, const float* __restrict__ x1,
                       u16* __restrict__ A0)
{
  const int idx = blockIdx.x * blockDim.x + threadIdx.x;
  const int m = idx >> 7;        // 128 4-elem chunks per row
  const int c = idx & 127;
  const float* src = (c < 64) ? (x0 + (size_t)m * 256 + c * 4)
                              : (x1 + (size_t)m * 256 + (c - 64) * 4);
  const float4 v = *(const float4*)src;
  uint2 pk;
  pk.x = (unsigned)f2bf(v.x) | ((unsigned)f2bf(v.y) << 16);
  pk.y = (unsigned)f2bf(v.z) | ((unsigned)f2bf(v.w) << 16);
  *(uint2*)&A0[(size_t)m * 512 + c * 4] = pk;
}

// Wt[N,K] bf16 <- W[K,N] f32, 32x32 LDS tile transpose.
__global__ void transpose_cast(const float* __restrict__ W, u16* __restrict__ Wt,
                               int K, int N)
{
  __shared__ float tile[32][33];
  const int tx = threadIdx.x & 31;
  const int ty = threadIdx.x >> 5;  // 0..7
  const int k0 = blockIdx.x * 32;
  const int n0 = blockIdx.y * 32;
#pragma unroll
  for (int i = 0; i < 32; i += 8)
    tile[ty + i][tx] = W[(size_t)(k0 + ty + i) * N + n0 + tx];
  __syncthreads();
#pragma unroll
  for (int i = 0; i < 32; i += 8)
    Wt[(size_t)(n0 + ty + i) * K + k0 + tx] = f2bf(tile[tx][ty + i]);
}

extern "C" void kernel_launch(void* const* d_in, const int* in_sizes, int n_in,
                              void* d_out, int out_size, void* d_ws, size_t ws_size,
                              hipStream_t stream)
{
  const float* x0 = (const float*)d_in[0];
  const float* x1 = (const float*)d_in[1];
  const float* t  = (const float*)d_in[2];
  const float* W1 = (const float*)d_in[3];
  const float* b1 = (const float*)d_in[4];
  const float* W2 = (const float*)d_in[5];
  const float* b2 = (const float*)d_in[6];
  const float* W3 = (const float*)d_in[7];
  const float* b3 = (const float*)d_in[8];
  const float* W4 = (const float*)d_in[9];
  const float* b4 = (const float*)d_in[10];

  char* ws = (char*)d_ws;
  const size_t WB1 = (size_t)512 * HDIM * 2;   // 1 MiB
  const size_t WB2 = (size_t)HDIM * HDIM * 2;  // 2 MiB
  const size_t WB4 = (size_t)HDIM * SDIM * 2;  // 0.5 MiB
  u16* Wt1 = (u16*)(ws);
  u16* Wt2 = (u16*)(ws + WB1);
  u16* Wt3 = (u16*)(ws + WB1 + WB2);
  u16* Wt4 = (u16*)(ws + WB1 + 2 * WB2);
  const size_t wmark = WB1 + 2 * WB2 + WB4;    // 5.5 MiB
  char* act = ws + wmark;

  // Adaptive chunking: per-chunk activations = 4 buffers of CB*2048 B
  // (A0 chunk aliases the Hb buffer). Pick nc so everything fits ws_size.
  int nc = 1;
  while (nc < 64 && wmark + (size_t)(BATCH / nc) * 8192 > ws_size) nc <<= 1;
  const int CB = BATCH / nc;

  u16* Ha = (u16*)(act);
  u16* Ua = (u16*)(act + (size_t)CB * 2048);
  u16* Hb = (u16*)(act + (size_t)CB * 4096);
  u16* Ub = (u16*)(act + (size_t)CB * 6144);
  u16* A0c = Hb;  // alias: A0 chunk (CB*1024 B) dead after layer 1

  transpose_cast<<<dim3(16, 32), 256, 0, stream>>>(W1, Wt1, 512, HDIM);
  transpose_cast<<<dim3(32, 32), 256, 0, stream>>>(W2, Wt2, HDIM, HDIM);
  transpose_cast<<<dim3(32, 32), 256, 0, stream>>>(W3, Wt3, HDIM, HDIM);
  transpose_cast<<<dim3(32, 8),  256, 0, stream>>>(W4, Wt4, HDIM, SDIM);

  const float* r1 = W1 + (size_t)512 * HDIM;   // last row of W1
  float* out_xt = (float*)d_out;
  float* out_dt = (float*)d_out + (size_t)BATCH * SDIM;

  for (int c = 0; c < nc; ++c) {
    const size_t mb = (size_t)c * CB;
    const dim3 gMid(HDIM / BN, CB / BM);
    const dim3 gOut(SDIM / BN, CB / BM);

    prep_z<<<(CB * 128) / 256, 256, 0, stream>>>(x0 + mb * SDIM, x1 + mb * SDIM, A0c);

    { EpiArgs e{}; e.bias = b1; e.r1 = r1; e.t = t + mb;
      e.out_h = Ha; e.out_u = Ua;
      fgemm<0, false><<<gMid, 256, 0, stream>>>(A0c, nullptr, Wt1, HDIM, 512, e); }

    { EpiArgs e{}; e.bias = b2; e.out_h = Hb; e.out_u = Ub;
      fgemm<1, true><<<gMid, 256, 0, stream>>>(Ha, Ua, Wt2, HDIM, HDIM, e); }

    { EpiArgs e{}; e.bias = b3; e.out_h = Ha; e.out_u = Ua;
      fgemm<1, true><<<gMid, 256, 0, stream>>>(Hb, Ub, Wt3, HDIM, HDIM, e); }

    { EpiArgs e{}; e.bias = b4; e.t = t + mb;
      e.x0 = x0 + mb * SDIM; e.x1 = x1 + mb * SDIM;
      e.out_xt = out_xt + mb * SDIM; e.out_dt = out_dt + mb * SDIM;
      fgemm<2, true><<<gOut, 256, 0, stream>>>(Ha, Ua, Wt4, SDIM, HDIM, e); }
  }
}